// Round 9
// baseline (214.747 us; speedup 1.0000x reference)
//
#include <hip/hip_runtime.h>

#define DD 128
#define NPB_LOG 8
#define NPB 256      // nodes per bucket
#define EPB 2048     // edges per chunk

typedef __attribute__((ext_vector_type(8))) short short8;
typedef __attribute__((ext_vector_type(4))) float f32x4;
typedef __attribute__((ext_vector_type(2))) float f32x2;

__device__ inline unsigned short f2bf(float f) {
    unsigned u = __float_as_uint(f);
    unsigned r = u + 0x7fffu + ((u >> 16) & 1u);
    return (unsigned short)(r >> 16);
}

// ---- phase1: sortA(histogram) FIRST, then prep(16), then bn_stats(1024) ----
__global__ __launch_bounds__(256) void phase1_k(
    const float4* __restrict__ x, float* __restrict__ stats16, int n,
    const int* __restrict__ dst, int nE, int NCHUNK, int NBUCK,
    const float* __restrict__ Wself, const float* __restrict__ Wneigh,
    unsigned short* __restrict__ Bpre, int* __restrict__ cm) {
    int b = blockIdx.x, tid = threadIdx.x;
    __shared__ float ls[8][256];  // 8 KB, aliased as int in sortA branch
    if (b < NCHUNK) {
        // ---- sortA: LDS histogram of this chunk's edges by dst bucket ----
        int chunk = b;
        int* cnt = (int*)ls;
        for (int i = tid; i < NBUCK; i += 256) cnt[i] = 0;
        __syncthreads();
        int e0 = chunk * EPB;
#pragma unroll
        for (int j = 0; j < 8; ++j) {
            int e = e0 + j * 256 + tid;
            if (e < nE) atomicAdd(&cnt[dst[e] >> NPB_LOG], 1);
        }
        __syncthreads();
        for (int bk = tid; bk < NBUCK; bk += 256)
            cm[(size_t)bk * NCHUNK + chunk] = cnt[bk];
    } else if (b < NCHUNK + 16) {
        // ---- prep: swizzle [Wself+I; Wneigh] -> bf16 MFMA fragment order ----
        int q = (b - NCHUNK) * 256 + tid;  // 0..4095
        int l = q & 63;
        int kb = ((q >> 9) << 5) + ((l >> 4) << 3);
        int nn = (((q >> 6) & 7) << 4) + (l & 15);
        bool self = (kb < 128);
        const float* Wp = self ? (Wself + (size_t)kb * 128 + nn)
                               : (Wneigh + (size_t)(kb - 128) * 128 + nn);
        unsigned tmp[4];
#pragma unroll
        for (int j = 0; j < 4; ++j) {
            float v0 = Wp[(2 * j) * 128];
            float v1 = Wp[(2 * j + 1) * 128];
            if (self) {  // fold skip connection: W_self + I
                if (kb + 2 * j == nn) v0 += 1.0f;
                if (kb + 2 * j + 1 == nn) v1 += 1.0f;
            }
            tmp[j] = (unsigned)f2bf(v0) | ((unsigned)f2bf(v1) << 16);
        }
        uint4 w; w.x = tmp[0]; w.y = tmp[1]; w.z = tmp[2]; w.w = tmp[3];
        *(uint4*)(Bpre + (size_t)q * 8) = w;
    } else {
        // ---- BN stats: sum & sumsq per feature, atomics sharded x16 ----
        int bb = b - NCHUNK - 16;
        int c4 = tid & 31, sub = tid >> 5;
        float sx = 0.f, sy = 0.f, sz = 0.f, sw = 0.f;
        float qx = 0.f, qy = 0.f, qz = 0.f, qw = 0.f;
        for (int r = bb * 8 + sub; r < n; r += 1024 * 8) {
            float4 v = x[(size_t)r * 32 + c4];
            sx += v.x; sy += v.y; sz += v.z; sw += v.w;
            qx += v.x * v.x; qy += v.y * v.y; qz += v.z * v.z; qw += v.w * v.w;
        }
        ls[sub][c4 * 4 + 0] = sx; ls[sub][c4 * 4 + 1] = sy;
        ls[sub][c4 * 4 + 2] = sz; ls[sub][c4 * 4 + 3] = sw;
        ls[sub][128 + c4 * 4 + 0] = qx; ls[sub][128 + c4 * 4 + 1] = qy;
        ls[sub][128 + c4 * 4 + 2] = qz; ls[sub][128 + c4 * 4 + 3] = qw;
        __syncthreads();
        float t = 0.f;
#pragma unroll
        for (int k = 0; k < 8; ++k) t += ls[k][tid];
        atomicAdd(&stats16[(bb & 15) * 256 + tid], t);
    }
}

// ---- scanF: single-pass decoupled-lookback scan over cm + BN finalize ------
// 150 blocks (<=256 CUs -> all co-resident, spin-wait safe). desc[b] packs
// flag<<32|value (1=aggregate, 2=inclusive prefix); device-scope atomics for
// cross-XCD visibility (G16). Replaces scanA+scanB+scanC (3 dispatches -> 1).
__global__ __launch_bounds__(256) void scanF_k(
    const int* __restrict__ v_in, unsigned long long* __restrict__ desc,
    int* __restrict__ out, int nCM,
    const float* __restrict__ stats16, const float* __restrict__ gamma,
    const float* __restrict__ beta, float* __restrict__ scsh, float inv_n) {
    int b = blockIdx.x, t = threadIdx.x;
    if (b == 0 && t < 128) {
        float s = 0.f, q = 0.f;
#pragma unroll
        for (int sh = 0; sh < 16; ++sh) {
            s += stats16[sh * 256 + t];
            q += stats16[sh * 256 + 128 + t];
        }
        float mean = s * inv_n;
        float var = q * inv_n - mean * mean;
        float sc = rsqrtf(var + 1e-5f) * gamma[t];
        scsh[t] = sc;
        scsh[128 + t] = beta[t] - mean * sc;
    }
    int i0 = b * 1024 + t * 4;
    int4 v = {0, 0, 0, 0};
    if (i0 + 3 < nCM) v = *(const int4*)(v_in + i0);
    else {
        if (i0 < nCM) v.x = v_in[i0];
        if (i0 + 1 < nCM) v.y = v_in[i0 + 1];
        if (i0 + 2 < nCM) v.z = v_in[i0 + 2];
    }
    int s4 = v.x + v.y + v.z + v.w;
    __shared__ int ls[256];
    __shared__ int sExcl;
    ls[t] = s4;
    __syncthreads();
#pragma unroll
    for (int off = 1; off < 256; off <<= 1) {
        int x = (t >= off) ? ls[t - off] : 0;
        __syncthreads();
        ls[t] += x;
        __syncthreads();
    }
    if (t == 0) {
        int blockTotal = ls[255];
        __hip_atomic_store(&desc[b], (1ull << 32) | (unsigned)blockTotal,
                           __ATOMIC_RELEASE, __HIP_MEMORY_SCOPE_AGENT);
        int excl = 0;
        for (int i = b - 1; i >= 0;) {
            unsigned long long d;
            do {
                d = __hip_atomic_load(&desc[i], __ATOMIC_ACQUIRE,
                                      __HIP_MEMORY_SCOPE_AGENT);
            } while ((d >> 32) == 0ull);
            excl += (int)(unsigned)d;
            if ((d >> 32) == 2ull) break;
            --i;
        }
        __hip_atomic_store(&desc[b],
                           (2ull << 32) | (unsigned)(excl + blockTotal),
                           __ATOMIC_RELEASE, __HIP_MEMORY_SCOPE_AGENT);
        sExcl = excl;
    }
    __syncthreads();
    int run = sExcl + ((t == 0) ? 0 : ls[t - 1]);
    int4 o;
    o.x = run; o.y = run + v.x; o.z = o.y + v.y; o.w = o.z + v.z;
    if (i0 + 3 < nCM) *(int4*)(out + i0) = o;
    else {
        if (i0 < nCM) out[i0] = o.x;
        if (i0 + 1 < nCM) out[i0 + 1] = o.y;
        if (i0 + 2 < nCM) out[i0 + 2] = o.z;
    }
}

// ---- phase2: sortB (LDS-staged, coalesced pairs writes) + normalize --------
__global__ __launch_bounds__(256) void phase2_k(
    const float4* __restrict__ x, const float* __restrict__ scsh,
    uint2* __restrict__ hbuf, unsigned* __restrict__ h8, int n,
    const int* __restrict__ src, const int* __restrict__ dst,
    const int* __restrict__ cmscan, unsigned* __restrict__ pairs,
    int nE, int NCHUNK, int NBUCK) {
    int b = blockIdx.x, tid = threadIdx.x;
    __shared__ int a[512];                 // hist -> exclusive scan (lofs)
    __shared__ int lcur[512];              // placement cursors
    __shared__ int bas[512];               // global run bases
    __shared__ unsigned lsorted[EPB];      // locally sorted pairs
    __shared__ unsigned short lbk[EPB];    // bucket id per sorted position
    if (b < NCHUNK) {
        int chunk = b;
        int e0 = chunk * EPB;
        int nv = min(EPB, nE - e0);
        for (int i = tid; i < 512; i += 256) a[i] = 0;
        __syncthreads();
        int myd[8];
#pragma unroll
        for (int j = 0; j < 8; ++j) {
            int e = e0 + j * 256 + tid;
            int d = (e < nE) ? dst[e] : -1;
            myd[j] = d;
            if (d >= 0) atomicAdd(&a[d >> NPB_LOG], 1);
        }
        for (int bk = tid; bk < NBUCK; bk += 256)
            bas[bk] = cmscan[(size_t)bk * NCHUNK + chunk];
        __syncthreads();
        // Blelloch exclusive scan of a[0..511]
        for (int d = 1; d < 512; d <<= 1) {
            int idx = (tid + 1) * (d << 1) - 1;
            if (idx < 512) a[idx] += a[idx - d];
            __syncthreads();
        }
        if (tid == 0) a[511] = 0;
        __syncthreads();
        for (int d = 256; d >= 1; d >>= 1) {
            int idx = (tid + 1) * (d << 1) - 1;
            if (idx < 512) { int tm = a[idx - d]; a[idx - d] = a[idx]; a[idx] += tm; }
            __syncthreads();
        }
        for (int i = tid; i < 512; i += 256) lcur[i] = a[i];
        __syncthreads();
#pragma unroll
        for (int j = 0; j < 8; ++j) {
            int d = myd[j];
            if (d >= 0) {
                int e = e0 + j * 256 + tid;
                int bk = d >> NPB_LOG;
                int lp = atomicAdd(&lcur[bk], 1);
                lsorted[lp] = ((unsigned)src[e] << NPB_LOG) | (unsigned)(d & (NPB - 1));
                lbk[lp] = (unsigned short)bk;
            }
        }
        __syncthreads();
        for (int i = tid; i < nv; i += 256) {
            int bk = lbk[i];
            pairs[bas[bk] + i - a[bk]] = lsorted[i];
        }
    } else {
        // ---- normalize: 16 rows/block, 2 independent rows per thread ------
        int blk = b - NCHUNK;
        int c4 = tid & 31, sub = tid >> 5;
        int r0 = blk * 16 + sub, r1 = r0 + 8;
        float4 sc = ((const float4*)scsh)[c4];
        float4 sh = ((const float4*)(scsh + 128))[c4];
        bool ok0 = r0 < n, ok1 = r1 < n;
        float4 v0, v1;
        if (ok0) v0 = x[(size_t)r0 * 32 + c4];
        if (ok1) v1 = x[(size_t)r1 * 32 + c4];
        if (ok0) {
            float hx = v0.x * sc.x + sh.x, hy = v0.y * sc.y + sh.y;
            float hz = v0.z * sc.z + sh.z, hw = v0.w * sc.w + sh.w;
            uint2 o;
            o.x = (unsigned)f2bf(hx) | ((unsigned)f2bf(hy) << 16);
            o.y = (unsigned)f2bf(hz) | ((unsigned)f2bf(hw) << 16);
            hbuf[(size_t)r0 * 32 + c4] = o;
            int p8 = __builtin_amdgcn_cvt_pk_fp8_f32(hx, hy, 0, false);
            p8 = __builtin_amdgcn_cvt_pk_fp8_f32(hz, hw, p8, true);
            h8[(size_t)r0 * 32 + c4] = (unsigned)p8;
        }
        if (ok1) {
            float hx = v1.x * sc.x + sh.x, hy = v1.y * sc.y + sh.y;
            float hz = v1.z * sc.z + sh.z, hw = v1.w * sc.w + sh.w;
            uint2 o;
            o.x = (unsigned)f2bf(hx) | ((unsigned)f2bf(hy) << 16);
            o.y = (unsigned)f2bf(hz) | ((unsigned)f2bf(hw) << 16);
            hbuf[(size_t)r1 * 32 + c4] = o;
            int p8 = __builtin_amdgcn_cvt_pk_fp8_f32(hx, hy, 0, false);
            p8 = __builtin_amdgcn_cvt_pk_fp8_f32(hz, hw, p8, true);
            h8[(size_t)r1 * 32 + c4] = (unsigned)p8;
        }
    }
}

// ---- sortC: per-bucket fine counting sort -> offsets + csr (LDS only) ------
__global__ __launch_bounds__(256) void sortC_k(
    const unsigned* __restrict__ pairs, const int* __restrict__ cmscan,
    int* __restrict__ offsets, int* __restrict__ csr,
    int n, int nE, int NCHUNK, int NBUCK) {
    int b = blockIdx.x, tid = threadIdx.x;
    int base0 = cmscan[(size_t)b * NCHUNK];
    int end = (b + 1 < NBUCK) ? cmscan[(size_t)(b + 1) * NCHUNK] : nE;
    __shared__ int cnt[NPB];
    __shared__ int cur[NPB];
    cnt[tid] = 0;
    __syncthreads();
    for (int e = base0 + tid; e < end; e += 256)
        atomicAdd(&cnt[pairs[e] & (NPB - 1)], 1);
    __syncthreads();
    int c0 = cnt[tid];
    __shared__ int ps[256];
    ps[tid] = c0;
    __syncthreads();
#pragma unroll
    for (int off = 1; off < 256; off <<= 1) {
        int v = (tid >= off) ? ps[tid - off] : 0;
        __syncthreads();
        ps[tid] += v;
        __syncthreads();
    }
    int ex = base0 + ps[tid] - c0;  // exclusive
    cur[tid] = ex;
    int node = b * NPB + tid;
    if (node < n) offsets[node] = ex;
    if (b == NBUCK - 1 && tid == 0) offsets[n] = nE;
    __syncthreads();
    for (int e = base0 + tid; e < end; e += 256) {
        unsigned u = pairs[e];
        int p = atomicAdd(&cur[u & (NPB - 1)], 1);
        csr[p] = (int)(u >> NPB_LOG);
    }
}

// ---- pull: 8 nodes per wave (8 lanes/node, uint4 gathers), 4-edge unroll ---
#define ACC8(v)                                                       \
    do {                                                              \
        acc[0] += __builtin_amdgcn_cvt_pk_f32_fp8((v).x, false);      \
        acc[1] += __builtin_amdgcn_cvt_pk_f32_fp8((v).x, true);       \
        acc[2] += __builtin_amdgcn_cvt_pk_f32_fp8((v).y, false);      \
        acc[3] += __builtin_amdgcn_cvt_pk_f32_fp8((v).y, true);       \
        acc[4] += __builtin_amdgcn_cvt_pk_f32_fp8((v).z, false);      \
        acc[5] += __builtin_amdgcn_cvt_pk_f32_fp8((v).z, true);       \
        acc[6] += __builtin_amdgcn_cvt_pk_f32_fp8((v).w, false);      \
        acc[7] += __builtin_amdgcn_cvt_pk_f32_fp8((v).w, true);       \
    } while (0)

__global__ __launch_bounds__(256) void pull_k(
    const int* __restrict__ offsets, const int* __restrict__ csr,
    const uint4* __restrict__ h8q, uint4* __restrict__ hnw, int n) {
    int wv = (blockIdx.x * 256 + threadIdx.x) >> 6;  // wave id
    int lane = threadIdx.x & 63;
    int g = lane >> 3, sl = lane & 7;   // 8 nodes/wave, 8 lanes/node
    int node = wv * 8 + g;
    bool valid = node < n;
    int nc = valid ? node : (n - 1);
    int b0 = offsets[nc], b1 = offsets[nc + 1];
    f32x2 acc[8];
#pragma unroll
    for (int k = 0; k < 8; ++k) acc[k] = f32x2{0.f, 0.f};
    int j = b0;
    for (; j + 4 <= b1; j += 4) {
        int i0 = csr[j], i1 = csr[j + 1], i2 = csr[j + 2], i3 = csr[j + 3];
        uint4 v0 = h8q[(size_t)i0 * 8 + sl];
        uint4 v1 = h8q[(size_t)i1 * 8 + sl];
        uint4 v2 = h8q[(size_t)i2 * 8 + sl];
        uint4 v3 = h8q[(size_t)i3 * 8 + sl];
        ACC8(v0); ACC8(v1); ACC8(v2); ACC8(v3);
    }
    if (j + 2 <= b1) {
        int i0 = csr[j], i1 = csr[j + 1];
        uint4 v0 = h8q[(size_t)i0 * 8 + sl];
        uint4 v1 = h8q[(size_t)i1 * 8 + sl];
        ACC8(v0); ACC8(v1);
        j += 2;
    }
    if (j < b1) {
        int i0 = csr[j];
        uint4 v0 = h8q[(size_t)i0 * 8 + sl];
        ACC8(v0);
    }
    if (valid) {
        float rd = (b1 > b0) ? 1.0f / (float)(b1 - b0) : 0.0f;
        unsigned ow[8];
#pragma unroll
        for (int k = 0; k < 8; ++k)
            ow[k] = (unsigned)f2bf(acc[k].x * rd) |
                    ((unsigned)f2bf(acc[k].y * rd) << 16);
        uint4 o1; o1.x = ow[0]; o1.y = ow[1]; o1.z = ow[2]; o1.w = ow[3];
        uint4 o2; o2.x = ow[4]; o2.y = ow[5]; o2.z = ow[6]; o2.w = ow[7];
        hnw[(size_t)node * 16 + sl * 2] = o1;
        hnw[(size_t)node * 16 + sl * 2 + 1] = o2;
    }
}

// ---- gemm: one block per 128 rows, FULL 128 cols (A read once) -------------
__global__ __launch_bounds__(256, 2) void gemm_k(
    const unsigned short* __restrict__ h, const unsigned short* __restrict__ hn,
    const unsigned short* __restrict__ Bpre, const float* __restrict__ bias,
    float* __restrict__ out, int n) {
    __shared__ unsigned short Bsw[32768];  // 64 KB: full B, group g = s*8+c
    int tid = threadIdx.x, wave = tid >> 6, lane = tid & 63;
    int rb = blockIdx.x;
#pragma unroll
    for (int i = 0; i < 16; ++i) {
        int g = wave * 16 + i;            // 0..63
        __builtin_amdgcn_global_load_lds(
            (const __attribute__((address_space(1))) void*)(
                Bpre + ((size_t)g * 64 + lane) * 8),
            (__attribute__((address_space(3))) void*)(Bsw + (size_t)g * 512),
            16, 0, 0);
    }
    __syncthreads();

    int quad = lane >> 4, mrow = lane & 15;
    int r0 = rb * 128 + wave * 32;
    int rA0 = min(r0 + mrow, n - 1);
    int rA1 = min(r0 + 16 + mrow, n - 1);

    f32x4 zero = {0.0f, 0.0f, 0.0f, 0.0f};
    f32x4 acc[2][8];
#pragma unroll
    for (int m = 0; m < 2; ++m)
#pragma unroll
        for (int t = 0; t < 8; ++t) acc[m][t] = zero;

#pragma unroll
    for (int s = 0; s < 8; ++s) {
        int kb = s * 32 + quad * 8;
        short8 a0, a1;
        if (s < 4) {
            a0 = *(const short8*)(h + (size_t)rA0 * 128 + kb);
            a1 = *(const short8*)(h + (size_t)rA1 * 128 + kb);
        } else {
            int kk = kb - 128;
            a0 = *(const short8*)(hn + (size_t)rA0 * 128 + kk);
            a1 = *(const short8*)(hn + (size_t)rA1 * 128 + kk);
        }
#pragma unroll
        for (int tt = 0; tt < 8; ++tt) {
            short8 b = *(const short8*)(Bsw + ((size_t)(s * 8 + tt) * 64 + lane) * 8);
            acc[0][tt] = __builtin_amdgcn_mfma_f32_16x16x32_bf16(a0, b, acc[0][tt], 0, 0, 0);
            acc[1][tt] = __builtin_amdgcn_mfma_f32_16x16x32_bf16(a1, b, acc[1][tt], 0, 0, 0);
        }
    }

    float bi[8];
#pragma unroll
    for (int t = 0; t < 8; ++t) bi[t] = bias[t * 16 + mrow];
#pragma unroll
    for (int m = 0; m < 2; ++m) {
#pragma unroll
        for (int i = 0; i < 4; ++i) {
            int row = r0 + m * 16 + quad * 4 + i;
            if (row < n) {
#pragma unroll
                for (int t = 0; t < 8; ++t) {
                    int col = t * 16 + mrow;
                    float xv = acc[m][t][i] + bi[t];
                    float x2 = xv * xv;
                    float u = 0.7978845608f * xv * (1.0f + 0.044715f * x2);
                    float e = __expf(2.0f * u);
                    float th = 1.0f - 2.0f * __builtin_amdgcn_rcpf(e + 1.0f);
                    out[(size_t)row * 128 + col] = 0.5f * xv * (1.0f + th);
                }
            }
        }
    }
}

extern "C" void kernel_launch(void* const* d_in, const int* in_sizes, int n_in,
                              void* d_out, int out_size, void* d_ws, size_t ws_size,
                              hipStream_t stream) {
    const float* features = (const float*)d_in[0];
    const int* src = (const int*)d_in[1];
    const int* dst = (const int*)d_in[2];
    const float* gamma = (const float*)d_in[3];
    const float* beta = (const float*)d_in[4];
    const float* Wself = (const float*)d_in[5];
    const float* Wneigh = (const float*)d_in[6];
    const float* bias = (const float*)d_in[7];
    int n = in_sizes[0] / DD;
    int nE = in_sizes[1];
    int NCHUNK = (nE + EPB - 1) / EPB;          // 391
    int NBUCK = (n + NPB - 1) / NPB;            // 391
    int CM = NBUCK * NCHUNK;                    // 152,881
    int tilesCM = (CM + 1023) / 1024;           // 150 (co-resident for lookback)
    int nbNorm16 = (n + 15) / 16;               // 6250

    auto align1k = [](size_t x) { return (x + 1023) & ~(size_t)1023; };
    char* ws = (char*)d_ws;
    size_t off = 0;
    float* stats16 = (float*)(ws + off);       off += 16384;
    unsigned long long* desc = (unsigned long long*)(ws + off); off += 2048;
    size_t zeroBytes = off;                    // stats16 + desc in ONE memset
    float* scsh   = (float*)(ws + off);        off += 2048;
    int* cm       = (int*)(ws + off);          off += align1k((size_t)CM * 4);
    int* cmscan   = (int*)(ws + off);          off += align1k((size_t)CM * 4);
    int* offsets  = (int*)(ws + off);          off += align1k((size_t)(n + 1) * 4);
    int* csr      = (int*)(ws + off);          off += align1k((size_t)nE * 4);
    unsigned* pairs = (unsigned*)(ws + off);   off += align1k((size_t)nE * 4);
    unsigned short* Bpre = (unsigned short*)(ws + off); off += 65536;
    unsigned short* hbuf = (unsigned short*)(ws + off); off += (size_t)n * 256;
    unsigned short* hnbuf = (unsigned short*)(ws + off); off += (size_t)n * 256;
    unsigned* h8 = (unsigned*)(ws + off);      off += (size_t)n * 128;

    hipMemsetAsync(stats16, 0, zeroBytes, stream);

    phase1_k<<<NCHUNK + 16 + 1024, 256, 0, stream>>>(
        (const float4*)features, stats16, n, dst, nE, NCHUNK, NBUCK,
        Wself, Wneigh, Bpre, cm);
    scanF_k<<<tilesCM, 256, 0, stream>>>(cm, desc, cmscan, CM,
                                         stats16, gamma, beta, scsh,
                                         1.0f / (float)n);
    phase2_k<<<NCHUNK + nbNorm16, 256, 0, stream>>>(
        (const float4*)features, scsh, (uint2*)hbuf, h8, n,
        src, dst, cmscan, pairs, nE, NCHUNK, NBUCK);
    sortC_k<<<NBUCK, 256, 0, stream>>>(pairs, cmscan, offsets, csr, n, nE,
                                       NCHUNK, NBUCK);
    {
        int waves = (n + 7) / 8;
        int blocks = (waves * 64 + 255) / 256;
        pull_k<<<blocks, 256, 0, stream>>>(
            offsets, csr, (const uint4*)h8, (uint4*)hnbuf, n);
    }
    gemm_k<<<(n + 127) / 128, 256, 0, stream>>>(
        hbuf, hnbuf, Bpre, bias, (float*)d_out, n);
}

// Round 10
// 197.176 us; speedup vs baseline: 1.0891x; 1.0891x over previous
//
#include <hip/hip_runtime.h>

#define DD 128
#define NPB_LOG 8
#define NPB 256      // nodes per bucket
#define EPB 2048     // edges per chunk

typedef __attribute__((ext_vector_type(8))) short short8;
typedef __attribute__((ext_vector_type(4))) float f32x4;
typedef __attribute__((ext_vector_type(2))) float f32x2;

__device__ inline unsigned short f2bf(float f) {
    unsigned u = __float_as_uint(f);
    unsigned r = u + 0x7fffu + ((u >> 16) & 1u);
    return (unsigned short)(r >> 16);
}

// ---- phase1: sortA(histogram -> cm + bucketTotal), prep(16), bn_stats ------
__global__ __launch_bounds__(256) void phase1_k(
    const float4* __restrict__ x, float* __restrict__ stats16, int n,
    const int* __restrict__ dst, int nE, int NCHUNK, int NBUCK,
    const float* __restrict__ Wself, const float* __restrict__ Wneigh,
    unsigned short* __restrict__ Bpre, int* __restrict__ cm,
    int* __restrict__ bt) {
    int b = blockIdx.x, tid = threadIdx.x;
    __shared__ float ls[8][256];  // 8 KB, aliased as int in sortA branch
    if (b < NCHUNK) {
        // ---- sortA: LDS histogram of this chunk's edges by dst bucket ----
        int chunk = b;
        int* cnt = (int*)ls;
        for (int i = tid; i < NBUCK; i += 256) cnt[i] = 0;
        __syncthreads();
        int e0 = chunk * EPB;
#pragma unroll
        for (int j = 0; j < 8; ++j) {
            int e = e0 + j * 256 + tid;
            if (e < nE) atomicAdd(&cnt[dst[e] >> NPB_LOG], 1);
        }
        __syncthreads();
        for (int bk = tid; bk < NBUCK; bk += 256) {
            int c = cnt[bk];
            cm[(size_t)bk * NCHUNK + chunk] = c;
            if (c) atomicAdd(&bt[bk], c);  // ~153k atomics on 391 hot lines
        }
    } else if (b < NCHUNK + 16) {
        // ---- prep: swizzle [Wself+I; Wneigh] -> bf16 MFMA fragment order ----
        int q = (b - NCHUNK) * 256 + tid;  // 0..4095
        int l = q & 63;
        int kb = ((q >> 9) << 5) + ((l >> 4) << 3);
        int nn = (((q >> 6) & 7) << 4) + (l & 15);
        bool self = (kb < 128);
        const float* Wp = self ? (Wself + (size_t)kb * 128 + nn)
                               : (Wneigh + (size_t)(kb - 128) * 128 + nn);
        unsigned tmp[4];
#pragma unroll
        for (int j = 0; j < 4; ++j) {
            float v0 = Wp[(2 * j) * 128];
            float v1 = Wp[(2 * j + 1) * 128];
            if (self) {  // fold skip connection: W_self + I
                if (kb + 2 * j == nn) v0 += 1.0f;
                if (kb + 2 * j + 1 == nn) v1 += 1.0f;
            }
            tmp[j] = (unsigned)f2bf(v0) | ((unsigned)f2bf(v1) << 16);
        }
        uint4 w; w.x = tmp[0]; w.y = tmp[1]; w.z = tmp[2]; w.w = tmp[3];
        *(uint4*)(Bpre + (size_t)q * 8) = w;
    } else {
        // ---- BN stats: sum & sumsq per feature, atomics sharded x16 ----
        int bb = b - NCHUNK - 16;
        int c4 = tid & 31, sub = tid >> 5;
        float sx = 0.f, sy = 0.f, sz = 0.f, sw = 0.f;
        float qx = 0.f, qy = 0.f, qz = 0.f, qw = 0.f;
        for (int r = bb * 8 + sub; r < n; r += 1024 * 8) {
            float4 v = x[(size_t)r * 32 + c4];
            sx += v.x; sy += v.y; sz += v.z; sw += v.w;
            qx += v.x * v.x; qy += v.y * v.y; qz += v.z * v.z; qw += v.w * v.w;
        }
        ls[sub][c4 * 4 + 0] = sx; ls[sub][c4 * 4 + 1] = sy;
        ls[sub][c4 * 4 + 2] = sz; ls[sub][c4 * 4 + 3] = sw;
        ls[sub][128 + c4 * 4 + 0] = qx; ls[sub][128 + c4 * 4 + 1] = qy;
        ls[sub][128 + c4 * 4 + 2] = qz; ls[sub][128 + c4 * 4 + 3] = qw;
        __syncthreads();
        float t = 0.f;
#pragma unroll
        for (int k = 0; k < 8; ++k) t += ls[k][tid];
        atomicAdd(&stats16[(bb & 15) * 256 + tid], t);
    }
}

// ---- scanR: one block per bucket row; no cross-block sync needed -----------
// cmscan[bk][c] = exclScan(bt)[bk] + exclScan(cm[bk][*])[c]. Every block
// redundantly scans the 391 bucket totals in LDS (cheap), then scans its own
// contiguous cm row. Block 0 also finalizes BN stats. Replaces scanA/B/C.
__global__ __launch_bounds__(256) void scanR_k(
    const int* __restrict__ cm, const int* __restrict__ bt,
    int* __restrict__ cmscan, int NCHUNK, int NBUCK,
    const float* __restrict__ stats16, const float* __restrict__ gamma,
    const float* __restrict__ beta, float* __restrict__ scsh, float inv_n) {
    int b = blockIdx.x, t = threadIdx.x;
    if (b == 0 && t < 128) {
        float s = 0.f, q = 0.f;
#pragma unroll
        for (int sh = 0; sh < 16; ++sh) {
            s += stats16[sh * 256 + t];
            q += stats16[sh * 256 + 128 + t];
        }
        float mean = s * inv_n;
        float var = q * inv_n - mean * mean;
        float sc = rsqrtf(var + 1e-5f) * gamma[t];
        scsh[t] = sc;
        scsh[128 + t] = beta[t] - mean * sc;
    }
    __shared__ int a[512];
    // ---- pass 1: exclusive scan of bucket totals -> base for this bucket --
    for (int i = t; i < 512; i += 256) a[i] = (i < NBUCK) ? bt[i] : 0;
    __syncthreads();
    for (int d = 1; d < 512; d <<= 1) {
        int idx = (t + 1) * (d << 1) - 1;
        if (idx < 512) a[idx] += a[idx - d];
        __syncthreads();
    }
    if (t == 0) a[511] = 0;
    __syncthreads();
    for (int d = 256; d >= 1; d >>= 1) {
        int idx = (t + 1) * (d << 1) - 1;
        if (idx < 512) { int tm = a[idx - d]; a[idx - d] = a[idx]; a[idx] += tm; }
        __syncthreads();
    }
    int base = a[b];
    __syncthreads();
    // ---- pass 2: exclusive scan of this bucket's chunk counts -------------
    for (int i = t; i < 512; i += 256)
        a[i] = (i < NCHUNK) ? cm[(size_t)b * NCHUNK + i] : 0;
    __syncthreads();
    for (int d = 1; d < 512; d <<= 1) {
        int idx = (t + 1) * (d << 1) - 1;
        if (idx < 512) a[idx] += a[idx - d];
        __syncthreads();
    }
    if (t == 0) a[511] = 0;
    __syncthreads();
    for (int d = 256; d >= 1; d >>= 1) {
        int idx = (t + 1) * (d << 1) - 1;
        if (idx < 512) { int tm = a[idx - d]; a[idx - d] = a[idx]; a[idx] += tm; }
        __syncthreads();
    }
    for (int c = t; c < NCHUNK; c += 256)
        cmscan[(size_t)b * NCHUNK + c] = base + a[c];
}

// ---- phase2: sortB (LDS-staged, coalesced pairs writes) + normalize --------
__global__ __launch_bounds__(256) void phase2_k(
    const float4* __restrict__ x, const float* __restrict__ scsh,
    uint2* __restrict__ hbuf, unsigned* __restrict__ h8, int n,
    const int* __restrict__ src, const int* __restrict__ dst,
    const int* __restrict__ cmscan, unsigned* __restrict__ pairs,
    int nE, int NCHUNK, int NBUCK) {
    int b = blockIdx.x, tid = threadIdx.x;
    __shared__ int a[512];                 // hist -> exclusive scan (lofs)
    __shared__ int lcur[512];              // placement cursors
    __shared__ int bas[512];               // global run bases
    __shared__ unsigned lsorted[EPB];      // locally sorted pairs
    __shared__ unsigned short lbk[EPB];    // bucket id per sorted position
    if (b < NCHUNK) {
        int chunk = b;
        int e0 = chunk * EPB;
        int nv = min(EPB, nE - e0);
        for (int i = tid; i < 512; i += 256) a[i] = 0;
        __syncthreads();
        int myd[8];
#pragma unroll
        for (int j = 0; j < 8; ++j) {
            int e = e0 + j * 256 + tid;
            int d = (e < nE) ? dst[e] : -1;
            myd[j] = d;
            if (d >= 0) atomicAdd(&a[d >> NPB_LOG], 1);
        }
        for (int bk = tid; bk < NBUCK; bk += 256)
            bas[bk] = cmscan[(size_t)bk * NCHUNK + chunk];
        __syncthreads();
        // Blelloch exclusive scan of a[0..511]
        for (int d = 1; d < 512; d <<= 1) {
            int idx = (tid + 1) * (d << 1) - 1;
            if (idx < 512) a[idx] += a[idx - d];
            __syncthreads();
        }
        if (tid == 0) a[511] = 0;
        __syncthreads();
        for (int d = 256; d >= 1; d >>= 1) {
            int idx = (tid + 1) * (d << 1) - 1;
            if (idx < 512) { int tm = a[idx - d]; a[idx - d] = a[idx]; a[idx] += tm; }
            __syncthreads();
        }
        for (int i = tid; i < 512; i += 256) lcur[i] = a[i];
        __syncthreads();
#pragma unroll
        for (int j = 0; j < 8; ++j) {
            int d = myd[j];
            if (d >= 0) {
                int e = e0 + j * 256 + tid;
                int bk = d >> NPB_LOG;
                int lp = atomicAdd(&lcur[bk], 1);
                lsorted[lp] = ((unsigned)src[e] << NPB_LOG) | (unsigned)(d & (NPB - 1));
                lbk[lp] = (unsigned short)bk;
            }
        }
        __syncthreads();
        for (int i = tid; i < nv; i += 256) {
            int bk = lbk[i];
            pairs[bas[bk] + i - a[bk]] = lsorted[i];
        }
    } else {
        // ---- normalize: 16 rows/block, 2 independent rows per thread ------
        int blk = b - NCHUNK;
        int c4 = tid & 31, sub = tid >> 5;
        int r0 = blk * 16 + sub, r1 = r0 + 8;
        float4 sc = ((const float4*)scsh)[c4];
        float4 sh = ((const float4*)(scsh + 128))[c4];
        bool ok0 = r0 < n, ok1 = r1 < n;
        float4 v0, v1;
        if (ok0) v0 = x[(size_t)r0 * 32 + c4];
        if (ok1) v1 = x[(size_t)r1 * 32 + c4];
        if (ok0) {
            float hx = v0.x * sc.x + sh.x, hy = v0.y * sc.y + sh.y;
            float hz = v0.z * sc.z + sh.z, hw = v0.w * sc.w + sh.w;
            uint2 o;
            o.x = (unsigned)f2bf(hx) | ((unsigned)f2bf(hy) << 16);
            o.y = (unsigned)f2bf(hz) | ((unsigned)f2bf(hw) << 16);
            hbuf[(size_t)r0 * 32 + c4] = o;
            int p8 = __builtin_amdgcn_cvt_pk_fp8_f32(hx, hy, 0, false);
            p8 = __builtin_amdgcn_cvt_pk_fp8_f32(hz, hw, p8, true);
            h8[(size_t)r0 * 32 + c4] = (unsigned)p8;
        }
        if (ok1) {
            float hx = v1.x * sc.x + sh.x, hy = v1.y * sc.y + sh.y;
            float hz = v1.z * sc.z + sh.z, hw = v1.w * sc.w + sh.w;
            uint2 o;
            o.x = (unsigned)f2bf(hx) | ((unsigned)f2bf(hy) << 16);
            o.y = (unsigned)f2bf(hz) | ((unsigned)f2bf(hw) << 16);
            hbuf[(size_t)r1 * 32 + c4] = o;
            int p8 = __builtin_amdgcn_cvt_pk_fp8_f32(hx, hy, 0, false);
            p8 = __builtin_amdgcn_cvt_pk_fp8_f32(hz, hw, p8, true);
            h8[(size_t)r1 * 32 + c4] = (unsigned)p8;
        }
    }
}

// ---- sortC: per-bucket fine counting sort -> offsets + csr (LDS only) ------
__global__ __launch_bounds__(256) void sortC_k(
    const unsigned* __restrict__ pairs, const int* __restrict__ cmscan,
    int* __restrict__ offsets, int* __restrict__ csr,
    int n, int nE, int NCHUNK, int NBUCK) {
    int b = blockIdx.x, tid = threadIdx.x;
    int base0 = cmscan[(size_t)b * NCHUNK];
    int end = (b + 1 < NBUCK) ? cmscan[(size_t)(b + 1) * NCHUNK] : nE;
    __shared__ int cnt[NPB];
    __shared__ int cur[NPB];
    cnt[tid] = 0;
    __syncthreads();
    for (int e = base0 + tid; e < end; e += 256)
        atomicAdd(&cnt[pairs[e] & (NPB - 1)], 1);
    __syncthreads();
    int c0 = cnt[tid];
    __shared__ int ps[256];
    ps[tid] = c0;
    __syncthreads();
#pragma unroll
    for (int off = 1; off < 256; off <<= 1) {
        int v = (tid >= off) ? ps[tid - off] : 0;
        __syncthreads();
        ps[tid] += v;
        __syncthreads();
    }
    int ex = base0 + ps[tid] - c0;  // exclusive
    cur[tid] = ex;
    int node = b * NPB + tid;
    if (node < n) offsets[node] = ex;
    if (b == NBUCK - 1 && tid == 0) offsets[n] = nE;
    __syncthreads();
    for (int e = base0 + tid; e < end; e += 256) {
        unsigned u = pairs[e];
        int p = atomicAdd(&cur[u & (NPB - 1)], 1);
        csr[p] = (int)(u >> NPB_LOG);
    }
}

// ---- pull: 8 nodes per wave (8 lanes/node, uint4 gathers), 4-edge unroll ---
#define ACC8(v)                                                       \
    do {                                                              \
        acc[0] += __builtin_amdgcn_cvt_pk_f32_fp8((v).x, false);      \
        acc[1] += __builtin_amdgcn_cvt_pk_f32_fp8((v).x, true);       \
        acc[2] += __builtin_amdgcn_cvt_pk_f32_fp8((v).y, false);      \
        acc[3] += __builtin_amdgcn_cvt_pk_f32_fp8((v).y, true);       \
        acc[4] += __builtin_amdgcn_cvt_pk_f32_fp8((v).z, false);      \
        acc[5] += __builtin_amdgcn_cvt_pk_f32_fp8((v).z, true);       \
        acc[6] += __builtin_amdgcn_cvt_pk_f32_fp8((v).w, false);      \
        acc[7] += __builtin_amdgcn_cvt_pk_f32_fp8((v).w, true);       \
    } while (0)

__global__ __launch_bounds__(256) void pull_k(
    const int* __restrict__ offsets, const int* __restrict__ csr,
    const uint4* __restrict__ h8q, uint4* __restrict__ hnw, int n) {
    int wv = (blockIdx.x * 256 + threadIdx.x) >> 6;  // wave id
    int lane = threadIdx.x & 63;
    int g = lane >> 3, sl = lane & 7;   // 8 nodes/wave, 8 lanes/node
    int node = wv * 8 + g;
    bool valid = node < n;
    int nc = valid ? node : (n - 1);
    int b0 = offsets[nc], b1 = offsets[nc + 1];
    f32x2 acc[8];
#pragma unroll
    for (int k = 0; k < 8; ++k) acc[k] = f32x2{0.f, 0.f};
    int j = b0;
    for (; j + 4 <= b1; j += 4) {
        int i0 = csr[j], i1 = csr[j + 1], i2 = csr[j + 2], i3 = csr[j + 3];
        uint4 v0 = h8q[(size_t)i0 * 8 + sl];
        uint4 v1 = h8q[(size_t)i1 * 8 + sl];
        uint4 v2 = h8q[(size_t)i2 * 8 + sl];
        uint4 v3 = h8q[(size_t)i3 * 8 + sl];
        ACC8(v0); ACC8(v1); ACC8(v2); ACC8(v3);
    }
    if (j + 2 <= b1) {
        int i0 = csr[j], i1 = csr[j + 1];
        uint4 v0 = h8q[(size_t)i0 * 8 + sl];
        uint4 v1 = h8q[(size_t)i1 * 8 + sl];
        ACC8(v0); ACC8(v1);
        j += 2;
    }
    if (j < b1) {
        int i0 = csr[j];
        uint4 v0 = h8q[(size_t)i0 * 8 + sl];
        ACC8(v0);
    }
    if (valid) {
        float rd = (b1 > b0) ? 1.0f / (float)(b1 - b0) : 0.0f;
        unsigned ow[8];
#pragma unroll
        for (int k = 0; k < 8; ++k)
            ow[k] = (unsigned)f2bf(acc[k].x * rd) |
                    ((unsigned)f2bf(acc[k].y * rd) << 16);
        uint4 o1; o1.x = ow[0]; o1.y = ow[1]; o1.z = ow[2]; o1.w = ow[3];
        uint4 o2; o2.x = ow[4]; o2.y = ow[5]; o2.z = ow[6]; o2.w = ow[7];
        hnw[(size_t)node * 16 + sl * 2] = o1;
        hnw[(size_t)node * 16 + sl * 2 + 1] = o2;
    }
}

// ---- gemm: one block per 128 rows, FULL 128 cols (A read once) -------------
__global__ __launch_bounds__(256, 2) void gemm_k(
    const unsigned short* __restrict__ h, const unsigned short* __restrict__ hn,
    const unsigned short* __restrict__ Bpre, const float* __restrict__ bias,
    float* __restrict__ out, int n) {
    __shared__ unsigned short Bsw[32768];  // 64 KB: full B, group g = s*8+c
    int tid = threadIdx.x, wave = tid >> 6, lane = tid & 63;
    int rb = blockIdx.x;
#pragma unroll
    for (int i = 0; i < 16; ++i) {
        int g = wave * 16 + i;            // 0..63
        __builtin_amdgcn_global_load_lds(
            (const __attribute__((address_space(1))) void*)(
                Bpre + ((size_t)g * 64 + lane) * 8),
            (__attribute__((address_space(3))) void*)(Bsw + (size_t)g * 512),
            16, 0, 0);
    }
    __syncthreads();

    int quad = lane >> 4, mrow = lane & 15;
    int r0 = rb * 128 + wave * 32;
    int rA0 = min(r0 + mrow, n - 1);
    int rA1 = min(r0 + 16 + mrow, n - 1);

    f32x4 zero = {0.0f, 0.0f, 0.0f, 0.0f};
    f32x4 acc[2][8];
#pragma unroll
    for (int m = 0; m < 2; ++m)
#pragma unroll
        for (int t = 0; t < 8; ++t) acc[m][t] = zero;

#pragma unroll
    for (int s = 0; s < 8; ++s) {
        int kb = s * 32 + quad * 8;
        short8 a0, a1;
        if (s < 4) {
            a0 = *(const short8*)(h + (size_t)rA0 * 128 + kb);
            a1 = *(const short8*)(h + (size_t)rA1 * 128 + kb);
        } else {
            int kk = kb - 128;
            a0 = *(const short8*)(hn + (size_t)rA0 * 128 + kk);
            a1 = *(const short8*)(hn + (size_t)rA1 * 128 + kk);
        }
#pragma unroll
        for (int tt = 0; tt < 8; ++tt) {
            short8 b = *(const short8*)(Bsw + ((size_t)(s * 8 + tt) * 64 + lane) * 8);
            acc[0][tt] = __builtin_amdgcn_mfma_f32_16x16x32_bf16(a0, b, acc[0][tt], 0, 0, 0);
            acc[1][tt] = __builtin_amdgcn_mfma_f32_16x16x32_bf16(a1, b, acc[1][tt], 0, 0, 0);
        }
    }

    float bi[8];
#pragma unroll
    for (int t = 0; t < 8; ++t) bi[t] = bias[t * 16 + mrow];
#pragma unroll
    for (int m = 0; m < 2; ++m) {
#pragma unroll
        for (int i = 0; i < 4; ++i) {
            int row = r0 + m * 16 + quad * 4 + i;
            if (row < n) {
#pragma unroll
                for (int t = 0; t < 8; ++t) {
                    int col = t * 16 + mrow;
                    float xv = acc[m][t][i] + bi[t];
                    float x2 = xv * xv;
                    float u = 0.7978845608f * xv * (1.0f + 0.044715f * x2);
                    float e = __expf(2.0f * u);
                    float th = 1.0f - 2.0f * __builtin_amdgcn_rcpf(e + 1.0f);
                    out[(size_t)row * 128 + col] = 0.5f * xv * (1.0f + th);
                }
            }
        }
    }
}

extern "C" void kernel_launch(void* const* d_in, const int* in_sizes, int n_in,
                              void* d_out, int out_size, void* d_ws, size_t ws_size,
                              hipStream_t stream) {
    const float* features = (const float*)d_in[0];
    const int* src = (const int*)d_in[1];
    const int* dst = (const int*)d_in[2];
    const float* gamma = (const float*)d_in[3];
    const float* beta = (const float*)d_in[4];
    const float* Wself = (const float*)d_in[5];
    const float* Wneigh = (const float*)d_in[6];
    const float* bias = (const float*)d_in[7];
    int n = in_sizes[0] / DD;
    int nE = in_sizes[1];
    int NCHUNK = (nE + EPB - 1) / EPB;          // 391
    int NBUCK = (n + NPB - 1) / NPB;            // 391 (<=512 for scanR)
    int CM = NBUCK * NCHUNK;                    // 152,881
    int nbNorm16 = (n + 15) / 16;               // 6250

    auto align1k = [](size_t x) { return (x + 1023) & ~(size_t)1023; };
    char* ws = (char*)d_ws;
    size_t off = 0;
    float* stats16 = (float*)(ws + off);       off += 16384;
    int* bt       = (int*)(ws + off);          off += 2048;
    size_t zeroBytes = off;                    // stats16 + bt in ONE memset
    float* scsh   = (float*)(ws + off);        off += 2048;
    int* cm       = (int*)(ws + off);          off += align1k((size_t)CM * 4);
    int* cmscan   = (int*)(ws + off);          off += align1k((size_t)CM * 4);
    int* offsets  = (int*)(ws + off);          off += align1k((size_t)(n + 1) * 4);
    int* csr      = (int*)(ws + off);          off += align1k((size_t)nE * 4);
    unsigned* pairs = (unsigned*)(ws + off);   off += align1k((size_t)nE * 4);
    unsigned short* Bpre = (unsigned short*)(ws + off); off += 65536;
    unsigned short* hbuf = (unsigned short*)(ws + off); off += (size_t)n * 256;
    unsigned short* hnbuf = (unsigned short*)(ws + off); off += (size_t)n * 256;
    unsigned* h8 = (unsigned*)(ws + off);      off += (size_t)n * 128;

    hipMemsetAsync(stats16, 0, zeroBytes, stream);

    phase1_k<<<NCHUNK + 16 + 1024, 256, 0, stream>>>(
        (const float4*)features, stats16, n, dst, nE, NCHUNK, NBUCK,
        Wself, Wneigh, Bpre, cm, bt);
    scanR_k<<<NBUCK, 256, 0, stream>>>(cm, bt, cmscan, NCHUNK, NBUCK,
                                       stats16, gamma, beta, scsh,
                                       1.0f / (float)n);
    phase2_k<<<NCHUNK + nbNorm16, 256, 0, stream>>>(
        (const float4*)features, scsh, (uint2*)hbuf, h8, n,
        src, dst, cmscan, pairs, nE, NCHUNK, NBUCK);
    sortC_k<<<NBUCK, 256, 0, stream>>>(pairs, cmscan, offsets, csr, n, nE,
                                       NCHUNK, NBUCK);
    {
        int waves = (n + 7) / 8;
        int blocks = (waves * 64 + 255) / 256;
        pull_k<<<blocks, 256, 0, stream>>>(
            offsets, csr, (const uint4*)h8, (uint4*)hnbuf, n);
    }
    gemm_k<<<(n + 127) / 128, 256, 0, stream>>>(
        hbuf, hnbuf, Bpre, bias, (float*)d_out, n);
}

// Round 11
// 190.534 us; speedup vs baseline: 1.1271x; 1.0349x over previous
//
#include <hip/hip_runtime.h>

#define DD 128
#define NPB_LOG 8
#define NPB 256      // nodes per bucket
#define EPB 2048     // edges per chunk

typedef __attribute__((ext_vector_type(8))) short short8;
typedef __attribute__((ext_vector_type(4))) float f32x4;
typedef __attribute__((ext_vector_type(2))) float f32x2;

__device__ inline unsigned short f2bf(float f) {
    unsigned u = __float_as_uint(f);
    unsigned r = u + 0x7fffu + ((u >> 16) & 1u);
    return (unsigned short)(r >> 16);
}

// ---- phase1: sortA(histogram) FIRST, then prep(16), then bn_stats(1024) ----
__global__ __launch_bounds__(256) void phase1_k(
    const float4* __restrict__ x, float* __restrict__ stats16, int n,
    const int* __restrict__ dst, int nE, int NCHUNK, int NBUCK,
    const float* __restrict__ Wself, const float* __restrict__ Wneigh,
    unsigned short* __restrict__ Bpre, int* __restrict__ cm) {
    int b = blockIdx.x, tid = threadIdx.x;
    __shared__ float ls[8][256];  // 8 KB, aliased as int in sortA branch
    if (b < NCHUNK) {
        // ---- sortA: LDS histogram of this chunk's edges by dst bucket ----
        int chunk = b;
        int* cnt = (int*)ls;
        for (int i = tid; i < NBUCK; i += 256) cnt[i] = 0;
        __syncthreads();
        int e0 = chunk * EPB;
#pragma unroll
        for (int j = 0; j < 8; ++j) {
            int e = e0 + j * 256 + tid;
            if (e < nE) atomicAdd(&cnt[dst[e] >> NPB_LOG], 1);
        }
        __syncthreads();
        for (int bk = tid; bk < NBUCK; bk += 256)
            cm[(size_t)bk * NCHUNK + chunk] = cnt[bk];
    } else if (b < NCHUNK + 16) {
        // ---- prep: swizzle [Wself+I; Wneigh] -> bf16 MFMA fragment order ----
        int q = (b - NCHUNK) * 256 + tid;  // 0..4095
        int l = q & 63;
        int kb = ((q >> 9) << 5) + ((l >> 4) << 3);
        int nn = (((q >> 6) & 7) << 4) + (l & 15);
        bool self = (kb < 128);
        const float* Wp = self ? (Wself + (size_t)kb * 128 + nn)
                               : (Wneigh + (size_t)(kb - 128) * 128 + nn);
        unsigned tmp[4];
#pragma unroll
        for (int j = 0; j < 4; ++j) {
            float v0 = Wp[(2 * j) * 128];
            float v1 = Wp[(2 * j + 1) * 128];
            if (self) {  // fold skip connection: W_self + I
                if (kb + 2 * j == nn) v0 += 1.0f;
                if (kb + 2 * j + 1 == nn) v1 += 1.0f;
            }
            tmp[j] = (unsigned)f2bf(v0) | ((unsigned)f2bf(v1) << 16);
        }
        uint4 w; w.x = tmp[0]; w.y = tmp[1]; w.z = tmp[2]; w.w = tmp[3];
        *(uint4*)(Bpre + (size_t)q * 8) = w;
    } else {
        // ---- BN stats: sum & sumsq per feature, atomics sharded x16 ----
        int bb = b - NCHUNK - 16;
        int c4 = tid & 31, sub = tid >> 5;
        float sx = 0.f, sy = 0.f, sz = 0.f, sw = 0.f;
        float qx = 0.f, qy = 0.f, qz = 0.f, qw = 0.f;
        for (int r = bb * 8 + sub; r < n; r += 1024 * 8) {
            float4 v = x[(size_t)r * 32 + c4];
            sx += v.x; sy += v.y; sz += v.z; sw += v.w;
            qx += v.x * v.x; qy += v.y * v.y; qz += v.z * v.z; qw += v.w * v.w;
        }
        ls[sub][c4 * 4 + 0] = sx; ls[sub][c4 * 4 + 1] = sy;
        ls[sub][c4 * 4 + 2] = sz; ls[sub][c4 * 4 + 3] = sw;
        ls[sub][128 + c4 * 4 + 0] = qx; ls[sub][128 + c4 * 4 + 1] = qy;
        ls[sub][128 + c4 * 4 + 2] = qz; ls[sub][128 + c4 * 4 + 3] = qw;
        __syncthreads();
        float t = 0.f;
#pragma unroll
        for (int k = 0; k < 8; ++k) t += ls[k][tid];
        atomicAdd(&stats16[(bb & 15) * 256 + tid], t);
    }
}

// ---- generic hierarchical scan (over the count matrix) ---------------------
__global__ __launch_bounds__(256) void scanA_k(
    const int* __restrict__ v_in, int* __restrict__ bsum, int n) {
    int b = blockIdx.x, t = threadIdx.x;
    int i0 = b * 1024 + t * 4;
    int4 v = {0, 0, 0, 0};
    if (i0 + 3 < n) v = *(const int4*)(v_in + i0);
    else {
        if (i0 < n) v.x = v_in[i0];
        if (i0 + 1 < n) v.y = v_in[i0 + 1];
        if (i0 + 2 < n) v.z = v_in[i0 + 2];
    }
    __shared__ int ls[256];
    ls[t] = v.x + v.y + v.z + v.w;
    __syncthreads();
#pragma unroll
    for (int off = 128; off > 0; off >>= 1) {
        if (t < off) ls[t] += ls[t + off];
        __syncthreads();
    }
    if (t == 0) bsum[b] = ls[0];
}

// scanB also finalizes BN stats -> scsh[0..127]=scale, scsh[128..255]=shift
__global__ __launch_bounds__(256) void scanB_k(
    const int* __restrict__ bsum, int* __restrict__ bpref,
    int* __restrict__ total_out, int nb, int n,
    const float* __restrict__ stats16, const float* __restrict__ gamma,
    const float* __restrict__ beta, float* __restrict__ scsh, float inv_n) {
    int t = threadIdx.x;
    if (t < 128) {
        float s = 0.f, q = 0.f;
#pragma unroll
        for (int sh = 0; sh < 16; ++sh) {
            s += stats16[sh * 256 + t];
            q += stats16[sh * 256 + 128 + t];
        }
        float mean = s * inv_n;
        float var = q * inv_n - mean * mean;
        float sc = rsqrtf(var + 1e-5f) * gamma[t];
        scsh[t] = sc;
        scsh[128 + t] = beta[t] - mean * sc;
    }
    __shared__ int ls[256];
    ls[t] = (t < nb) ? bsum[t] : 0;
    __syncthreads();
#pragma unroll
    for (int off = 1; off < 256; off <<= 1) {
        int x = (t >= off) ? ls[t - off] : 0;
        __syncthreads();
        ls[t] += x;
        __syncthreads();
    }
    if (t < nb) bpref[t] = (t == 0) ? 0 : ls[t - 1];
    if (t == nb - 1) total_out[n] = ls[t];
}

__global__ __launch_bounds__(256) void scanC_k(
    const int* __restrict__ v_in, const int* __restrict__ bpref,
    int* __restrict__ o1, int* __restrict__ o2, int n) {
    int b = blockIdx.x, t = threadIdx.x;
    int i0 = b * 1024 + t * 4;
    int4 v = {0, 0, 0, 0};
    if (i0 + 3 < n) v = *(const int4*)(v_in + i0);
    else {
        if (i0 < n) v.x = v_in[i0];
        if (i0 + 1 < n) v.y = v_in[i0 + 1];
        if (i0 + 2 < n) v.z = v_in[i0 + 2];
    }
    int s = v.x + v.y + v.z + v.w;
    __shared__ int ls[256];
    ls[t] = s;
    __syncthreads();
#pragma unroll
    for (int off = 1; off < 256; off <<= 1) {
        int x = (t >= off) ? ls[t - off] : 0;
        __syncthreads();
        ls[t] += x;
        __syncthreads();
    }
    int run = bpref[b] + ((t == 0) ? 0 : ls[t - 1]);
    int4 o;
    o.x = run; o.y = run + v.x; o.z = o.y + v.y; o.w = o.z + v.z;
    if (i0 + 3 < n) {
        *(int4*)(o1 + i0) = o;
        *(int4*)(o2 + i0) = o;
    } else {
        if (i0 < n) { o1[i0] = o.x; o2[i0] = o.x; }
        if (i0 + 1 < n) { o1[i0 + 1] = o.y; o2[i0 + 1] = o.y; }
        if (i0 + 2 < n) { o1[i0 + 2] = o.z; o2[i0 + 2] = o.z; }
    }
}

// ---- phase2: sortB (LDS-staged, coalesced pairs writes) + normalize --------
__global__ __launch_bounds__(256) void phase2_k(
    const float4* __restrict__ x, const float* __restrict__ scsh,
    uint2* __restrict__ hbuf, unsigned* __restrict__ h8, int n,
    const int* __restrict__ src, const int* __restrict__ dst,
    const int* __restrict__ cmscan, unsigned* __restrict__ pairs,
    int nE, int NCHUNK, int NBUCK) {
    int b = blockIdx.x, tid = threadIdx.x;
    __shared__ int a[512];                 // hist -> exclusive scan (lofs)
    __shared__ int lcur[512];              // placement cursors
    __shared__ int bas[512];               // global run bases
    __shared__ unsigned lsorted[EPB];      // locally sorted pairs
    __shared__ unsigned short lbk[EPB];    // bucket id per sorted position
    if (b < NCHUNK) {
        int chunk = b;
        int e0 = chunk * EPB;
        int nv = min(EPB, nE - e0);
        for (int i = tid; i < 512; i += 256) a[i] = 0;
        __syncthreads();
        int myd[8];
#pragma unroll
        for (int j = 0; j < 8; ++j) {
            int e = e0 + j * 256 + tid;
            int d = (e < nE) ? dst[e] : -1;
            myd[j] = d;
            if (d >= 0) atomicAdd(&a[d >> NPB_LOG], 1);
        }
        for (int bk = tid; bk < NBUCK; bk += 256)
            bas[bk] = cmscan[(size_t)bk * NCHUNK + chunk];
        __syncthreads();
        // Blelloch exclusive scan of a[0..511]
        for (int d = 1; d < 512; d <<= 1) {
            int idx = (tid + 1) * (d << 1) - 1;
            if (idx < 512) a[idx] += a[idx - d];
            __syncthreads();
        }
        if (tid == 0) a[511] = 0;
        __syncthreads();
        for (int d = 256; d >= 1; d >>= 1) {
            int idx = (tid + 1) * (d << 1) - 1;
            if (idx < 512) { int tm = a[idx - d]; a[idx - d] = a[idx]; a[idx] += tm; }
            __syncthreads();
        }
        for (int i = tid; i < 512; i += 256) lcur[i] = a[i];
        __syncthreads();
#pragma unroll
        for (int j = 0; j < 8; ++j) {
            int d = myd[j];
            if (d >= 0) {
                int e = e0 + j * 256 + tid;
                int bk = d >> NPB_LOG;
                int lp = atomicAdd(&lcur[bk], 1);
                lsorted[lp] = ((unsigned)src[e] << NPB_LOG) | (unsigned)(d & (NPB - 1));
                lbk[lp] = (unsigned short)bk;
            }
        }
        __syncthreads();
        for (int i = tid; i < nv; i += 256) {
            int bk = lbk[i];
            pairs[bas[bk] + i - a[bk]] = lsorted[i];
        }
    } else {
        // ---- normalize: 16 rows/block, 2 independent rows per thread ------
        int blk = b - NCHUNK;
        int c4 = tid & 31, sub = tid >> 5;
        int r0 = blk * 16 + sub, r1 = r0 + 8;
        float4 sc = ((const float4*)scsh)[c4];
        float4 sh = ((const float4*)(scsh + 128))[c4];
        bool ok0 = r0 < n, ok1 = r1 < n;
        float4 v0, v1;
        if (ok0) v0 = x[(size_t)r0 * 32 + c4];
        if (ok1) v1 = x[(size_t)r1 * 32 + c4];
        if (ok0) {
            float hx = v0.x * sc.x + sh.x, hy = v0.y * sc.y + sh.y;
            float hz = v0.z * sc.z + sh.z, hw = v0.w * sc.w + sh.w;
            uint2 o;
            o.x = (unsigned)f2bf(hx) | ((unsigned)f2bf(hy) << 16);
            o.y = (unsigned)f2bf(hz) | ((unsigned)f2bf(hw) << 16);
            hbuf[(size_t)r0 * 32 + c4] = o;
            int p8 = __builtin_amdgcn_cvt_pk_fp8_f32(hx, hy, 0, false);
            p8 = __builtin_amdgcn_cvt_pk_fp8_f32(hz, hw, p8, true);
            h8[(size_t)r0 * 32 + c4] = (unsigned)p8;
        }
        if (ok1) {
            float hx = v1.x * sc.x + sh.x, hy = v1.y * sc.y + sh.y;
            float hz = v1.z * sc.z + sh.z, hw = v1.w * sc.w + sh.w;
            uint2 o;
            o.x = (unsigned)f2bf(hx) | ((unsigned)f2bf(hy) << 16);
            o.y = (unsigned)f2bf(hz) | ((unsigned)f2bf(hw) << 16);
            hbuf[(size_t)r1 * 32 + c4] = o;
            int p8 = __builtin_amdgcn_cvt_pk_fp8_f32(hx, hy, 0, false);
            p8 = __builtin_amdgcn_cvt_pk_fp8_f32(hz, hw, p8, true);
            h8[(size_t)r1 * 32 + c4] = (unsigned)p8;
        }
    }
}

// ---- sortC: per-bucket fine counting sort, 512 threads (2x wave depth) -----
// 391 blocks is only ~1.5/CU; each block strides its ~2048-edge range twice.
// 512 threads halves the sequential latency-bound iterations per pass.
__global__ __launch_bounds__(512) void sortC_k(
    const unsigned* __restrict__ pairs, const int* __restrict__ cmscan,
    int* __restrict__ offsets, int* __restrict__ csr,
    int n, int nE, int NCHUNK, int NBUCK) {
    int b = blockIdx.x, tid = threadIdx.x;
    int base0 = cmscan[(size_t)b * NCHUNK];
    int end = (b + 1 < NBUCK) ? cmscan[(size_t)(b + 1) * NCHUNK] : nE;
    __shared__ int cnt[NPB];
    __shared__ int cur[NPB];
    __shared__ int ps[NPB];
    if (tid < NPB) cnt[tid] = 0;
    __syncthreads();
    for (int e = base0 + tid; e < end; e += 512)
        atomicAdd(&cnt[pairs[e] & (NPB - 1)], 1);
    __syncthreads();
    if (tid < NPB) ps[tid] = cnt[tid];
    __syncthreads();
#pragma unroll
    for (int off = 1; off < NPB; off <<= 1) {
        int v = (tid >= off && tid < NPB) ? ps[tid - off] : 0;
        __syncthreads();
        if (tid < NPB) ps[tid] += v;
        __syncthreads();
    }
    if (tid < NPB) {
        int ex = base0 + ps[tid] - cnt[tid];  // exclusive
        cur[tid] = ex;
        int node = b * NPB + tid;
        if (node < n) offsets[node] = ex;
        if (b == NBUCK - 1 && tid == 0) offsets[n] = nE;
    }
    __syncthreads();
    for (int e = base0 + tid; e < end; e += 512) {
        unsigned u = pairs[e];
        int p = atomicAdd(&cur[u & (NPB - 1)], 1);
        csr[p] = (int)(u >> NPB_LOG);
    }
}

// ---- pull: 8 nodes per wave (8 lanes/node, uint4 gathers), 8-edge unroll ---
#define ACC8(v)                                                       \
    do {                                                              \
        acc[0] += __builtin_amdgcn_cvt_pk_f32_fp8((v).x, false);      \
        acc[1] += __builtin_amdgcn_cvt_pk_f32_fp8((v).x, true);       \
        acc[2] += __builtin_amdgcn_cvt_pk_f32_fp8((v).y, false);      \
        acc[3] += __builtin_amdgcn_cvt_pk_f32_fp8((v).y, true);       \
        acc[4] += __builtin_amdgcn_cvt_pk_f32_fp8((v).z, false);      \
        acc[5] += __builtin_amdgcn_cvt_pk_f32_fp8((v).z, true);       \
        acc[6] += __builtin_amdgcn_cvt_pk_f32_fp8((v).w, false);      \
        acc[7] += __builtin_amdgcn_cvt_pk_f32_fp8((v).w, true);       \
    } while (0)

__global__ __launch_bounds__(256) void pull_k(
    const int* __restrict__ offsets, const int* __restrict__ csr,
    const uint4* __restrict__ h8q, uint4* __restrict__ hnw, int n) {
    int wv = (blockIdx.x * 256 + threadIdx.x) >> 6;  // wave id
    int lane = threadIdx.x & 63;
    int g = lane >> 3, sl = lane & 7;   // 8 nodes/wave, 8 lanes/node
    int node = wv * 8 + g;
    bool valid = node < n;
    int nc = valid ? node : (n - 1);
    int b0 = offsets[nc], b1 = offsets[nc + 1];
    f32x2 acc[8];
#pragma unroll
    for (int k = 0; k < 8; ++k) acc[k] = f32x2{0.f, 0.f};
    int j = b0;
    for (; j + 8 <= b1; j += 8) {
        int idx[8];
#pragma unroll
        for (int q = 0; q < 8; ++q) idx[q] = csr[j + q];
        uint4 v[8];
#pragma unroll
        for (int q = 0; q < 8; ++q) v[q] = h8q[(size_t)idx[q] * 8 + sl];
#pragma unroll
        for (int q = 0; q < 8; ++q) ACC8(v[q]);
    }
    if (j + 4 <= b1) {
        int i0 = csr[j], i1 = csr[j + 1], i2 = csr[j + 2], i3 = csr[j + 3];
        uint4 v0 = h8q[(size_t)i0 * 8 + sl];
        uint4 v1 = h8q[(size_t)i1 * 8 + sl];
        uint4 v2 = h8q[(size_t)i2 * 8 + sl];
        uint4 v3 = h8q[(size_t)i3 * 8 + sl];
        ACC8(v0); ACC8(v1); ACC8(v2); ACC8(v3);
        j += 4;
    }
    if (j + 2 <= b1) {
        int i0 = csr[j], i1 = csr[j + 1];
        uint4 v0 = h8q[(size_t)i0 * 8 + sl];
        uint4 v1 = h8q[(size_t)i1 * 8 + sl];
        ACC8(v0); ACC8(v1);
        j += 2;
    }
    if (j < b1) {
        int i0 = csr[j];
        uint4 v0 = h8q[(size_t)i0 * 8 + sl];
        ACC8(v0);
    }
    if (valid) {
        float rd = (b1 > b0) ? 1.0f / (float)(b1 - b0) : 0.0f;
        unsigned ow[8];
#pragma unroll
        for (int k = 0; k < 8; ++k)
            ow[k] = (unsigned)f2bf(acc[k].x * rd) |
                    ((unsigned)f2bf(acc[k].y * rd) << 16);
        uint4 o1; o1.x = ow[0]; o1.y = ow[1]; o1.z = ow[2]; o1.w = ow[3];
        uint4 o2; o2.x = ow[4]; o2.y = ow[5]; o2.z = ow[6]; o2.w = ow[7];
        hnw[(size_t)node * 16 + sl * 2] = o1;
        hnw[(size_t)node * 16 + sl * 2 + 1] = o2;
    }
}

// ---- gemm: one block per 128 rows, FULL 128 cols (A read once) -------------
__global__ __launch_bounds__(256, 2) void gemm_k(
    const unsigned short* __restrict__ h, const unsigned short* __restrict__ hn,
    const unsigned short* __restrict__ Bpre, const float* __restrict__ bias,
    float* __restrict__ out, int n) {
    __shared__ unsigned short Bsw[32768];  // 64 KB: full B, group g = s*8+c
    int tid = threadIdx.x, wave = tid >> 6, lane = tid & 63;
    int rb = blockIdx.x;
#pragma unroll
    for (int i = 0; i < 16; ++i) {
        int g = wave * 16 + i;            // 0..63
        __builtin_amdgcn_global_load_lds(
            (const __attribute__((address_space(1))) void*)(
                Bpre + ((size_t)g * 64 + lane) * 8),
            (__attribute__((address_space(3))) void*)(Bsw + (size_t)g * 512),
            16, 0, 0);
    }
    __syncthreads();

    int quad = lane >> 4, mrow = lane & 15;
    int r0 = rb * 128 + wave * 32;
    int rA0 = min(r0 + mrow, n - 1);
    int rA1 = min(r0 + 16 + mrow, n - 1);

    f32x4 zero = {0.0f, 0.0f, 0.0f, 0.0f};
    f32x4 acc[2][8];
#pragma unroll
    for (int m = 0; m < 2; ++m)
#pragma unroll
        for (int t = 0; t < 8; ++t) acc[m][t] = zero;

#pragma unroll
    for (int s = 0; s < 8; ++s) {
        int kb = s * 32 + quad * 8;
        short8 a0, a1;
        if (s < 4) {
            a0 = *(const short8*)(h + (size_t)rA0 * 128 + kb);
            a1 = *(const short8*)(h + (size_t)rA1 * 128 + kb);
        } else {
            int kk = kb - 128;
            a0 = *(const short8*)(hn + (size_t)rA0 * 128 + kk);
            a1 = *(const short8*)(hn + (size_t)rA1 * 128 + kk);
        }
#pragma unroll
        for (int tt = 0; tt < 8; ++tt) {
            short8 b = *(const short8*)(Bsw + ((size_t)(s * 8 + tt) * 64 + lane) * 8);
            acc[0][tt] = __builtin_amdgcn_mfma_f32_16x16x32_bf16(a0, b, acc[0][tt], 0, 0, 0);
            acc[1][tt] = __builtin_amdgcn_mfma_f32_16x16x32_bf16(a1, b, acc[1][tt], 0, 0, 0);
        }
    }

    float bi[8];
#pragma unroll
    for (int t = 0; t < 8; ++t) bi[t] = bias[t * 16 + mrow];
#pragma unroll
    for (int m = 0; m < 2; ++m) {
#pragma unroll
        for (int i = 0; i < 4; ++i) {
            int row = r0 + m * 16 + quad * 4 + i;
            if (row < n) {
#pragma unroll
                for (int t = 0; t < 8; ++t) {
                    int col = t * 16 + mrow;
                    float xv = acc[m][t][i] + bi[t];
                    float x2 = xv * xv;
                    float u = 0.7978845608f * xv * (1.0f + 0.044715f * x2);
                    float e = __expf(2.0f * u);
                    float th = 1.0f - 2.0f * __builtin_amdgcn_rcpf(e + 1.0f);
                    out[(size_t)row * 128 + col] = 0.5f * xv * (1.0f + th);
                }
            }
        }
    }
}

extern "C" void kernel_launch(void* const* d_in, const int* in_sizes, int n_in,
                              void* d_out, int out_size, void* d_ws, size_t ws_size,
                              hipStream_t stream) {
    const float* features = (const float*)d_in[0];
    const int* src = (const int*)d_in[1];
    const int* dst = (const int*)d_in[2];
    const float* gamma = (const float*)d_in[3];
    const float* beta = (const float*)d_in[4];
    const float* Wself = (const float*)d_in[5];
    const float* Wneigh = (const float*)d_in[6];
    const float* bias = (const float*)d_in[7];
    int n = in_sizes[0] / DD;
    int nE = in_sizes[1];
    int NCHUNK = (nE + EPB - 1) / EPB;          // 391
    int NBUCK = (n + NPB - 1) / NPB;            // 391
    int CM = NBUCK * NCHUNK;                    // 152,881
    int tilesCM = (CM + 1023) / 1024;           // 150 (<=256 for scanB)
    int nbNorm16 = (n + 15) / 16;               // 6250

    auto align1k = [](size_t x) { return (x + 1023) & ~(size_t)1023; };
    char* ws = (char*)d_ws;
    size_t off = 0;
    float* stats16 = (float*)(ws + off);       off += 16384;
    float* scsh   = (float*)(ws + off);        off += 2048;
    int* cm       = (int*)(ws + off);          off += align1k((size_t)(CM + 1) * 4);
    int* cmscan   = (int*)(ws + off);          off += align1k((size_t)CM * 4);
    int* offsets  = (int*)(ws + off);          off += align1k((size_t)(n + 1) * 4);
    int* csr      = (int*)(ws + off);          off += align1k((size_t)nE * 4);
    unsigned* pairs = (unsigned*)(ws + off);   off += align1k((size_t)nE * 4);
    int* bsum     = (int*)(ws + off);          off += 1024;
    int* bpref    = (int*)(ws + off);          off += 1024;
    unsigned short* Bpre = (unsigned short*)(ws + off); off += 65536;
    unsigned short* hbuf = (unsigned short*)(ws + off); off += (size_t)n * 256;
    unsigned short* hnbuf = (unsigned short*)(ws + off); off += (size_t)n * 256;
    unsigned* h8 = (unsigned*)(ws + off);      off += (size_t)n * 128;

    hipMemsetAsync(stats16, 0, 16384, stream);

    phase1_k<<<NCHUNK + 16 + 1024, 256, 0, stream>>>(
        (const float4*)features, stats16, n, dst, nE, NCHUNK, NBUCK,
        Wself, Wneigh, Bpre, cm);
    scanA_k<<<tilesCM, 256, 0, stream>>>(cm, bsum, CM);
    scanB_k<<<1, 256, 0, stream>>>(bsum, bpref, cm, tilesCM, CM,
                                   stats16, gamma, beta, scsh, 1.0f / (float)n);
    scanC_k<<<tilesCM, 256, 0, stream>>>(cm, bpref, cmscan, cmscan, CM);
    phase2_k<<<NCHUNK + nbNorm16, 256, 0, stream>>>(
        (const float4*)features, scsh, (uint2*)hbuf, h8, n,
        src, dst, cmscan, pairs, nE, NCHUNK, NBUCK);
    sortC_k<<<NBUCK, 512, 0, stream>>>(pairs, cmscan, offsets, csr, n, nE,
                                       NCHUNK, NBUCK);
    {
        int waves = (n + 7) / 8;
        int blocks = (waves * 64 + 255) / 256;
        pull_k<<<blocks, 256, 0, stream>>>(
            offsets, csr, (const uint4*)h8, (uint4*)hnbuf, n);
    }
    gemm_k<<<(n + 127) / 128, 256, 0, stream>>>(
        hbuf, hnbuf, Bpre, bias, (float*)d_out, n);
}